// Round 6
// baseline (205.026 us; speedup 1.0000x reference)
//
#include <hip/hip_runtime.h>
#include <stdint.h>

#define NIMG 32
#define CH 32
#define HH 160
#define WW 160
#define HWL (HH*WW)            // 25600
#define PRS 164                // padded row stride (words)
#define PHH 162
#define PIMG (PHH*PRS)         // 26568 words per padded image
#define NPIX (NIMG*HWL)        // 819200 pixels
#define HALO_WORDS 968         // per image: 2*164 + 160*4

// workspace layout (bytes)
#define OFF_P     0
#define OFF_P2    3400704                    // P : 32*26568*4
#define OFF_INNER (OFF_P2 + 3400704)         // P2: same
#define OFF_WP    (OFF_INNER + 52428800)     // inner: bf16
#define OFF_CORR  (OFF_WP + 2304)
#define OFF_SC    (OFF_CORR + 2304)
#define OFF_SB    (OFF_SC + 128)             // 64 StatLines x 128 B

struct StatLine {                            // one 128B line per channel
  int s1; int pad0; unsigned long long s2; char pad[112];
};

__device__ __forceinline__ unsigned short f2bf(float f) {   // RNE float->bf16
  unsigned u = __float_as_uint(f);
  u += 0x7fffu + ((u >> 16) & 1u);
  return (unsigned short)(u >> 16);
}
__device__ __forceinline__ float bf2f(unsigned short u) {
  return __uint_as_float((uint32_t)u << 16);
}

__device__ __forceinline__ void conv4(const uint32_t r[3][6], const uint32_t* wsh,
                                      int co, int& a0, int& a1, int& a2, int& a3)
{
  a0 = a1 = a2 = a3 = 0;
  #pragma unroll
  for (int dy = 0; dy < 3; ++dy) {
    #pragma unroll
    for (int dx = 0; dx < 3; ++dx) {
      uint32_t wvv = wsh[co * 9 + dy * 3 + dx];
      a0 += __popc(r[dy][0 + dx] ^ wvv);
      a1 += __popc(r[dy][1 + dx] ^ wvv);
      a2 += __popc(r[dy][2 + dx] ^ wvv);
      a3 += __popc(r[dy][3 + dx] ^ wvv);
    }
  }
}

// ================ K1: pack x (4 thr / 8-px group, 16 float4 in flight) + prep + halo
// blocks 0..1599: pack; 1600..1841: halo zero; 1842: prep
__global__ __launch_bounds__(256, 2) void pack_prep(const float* __restrict__ x,
    const float* __restrict__ w1, const float* __restrict__ w2,
    uint32_t* __restrict__ P, uint32_t* __restrict__ P2, uint32_t* __restrict__ WP,
    int* __restrict__ CORR, float* __restrict__ SC, StatLine* __restrict__ SB)
{
  __shared__ float red[256];
  const int tid = threadIdx.x;
  const int b = blockIdx.x;

  if (b >= 1600) {
    if (b == 1842) {
      // ---- prep: zero stats, weight scales, bit-pack, border corrections
      int* z = (int*)SB;
      for (int i = tid; i < 2048; i += 256) z[i] = 0;
      for (int cv = 0; cv < 2; ++cv) {
        const float* w = cv ? w2 : w1;
        float s = 0.f;
        for (int i = tid; i < 9216; i += 256) s += fabsf(w[i]);
        red[tid] = s;
        __syncthreads();
        for (int st = 128; st > 0; st >>= 1) {
          if (tid < st) red[tid] += red[tid + st];
          __syncthreads();
        }
        if (tid == 0) SC[cv] = red[0] / 9216.0f;
        for (int i = tid; i < 288; i += 256) {
          int co = i / 9, t = i - co * 9;
          uint32_t bw = 0;
          for (int ci = 0; ci < 32; ++ci)
            bw |= (w[(co * 32 + ci) * 9 + t] > 0.0f) ? (1u << ci) : 0u;
          WP[cv * 288 + i] = bw;
        }
        __syncthreads();
        for (int i = tid; i < 288; i += 256) {
          int cls = i / 32, co = i - cls * 32;
          int hc = cls / 3, wc = cls - hc * 3;
          int corr = 0;
          for (int t = 0; t < 9; ++t) {
            int dy = t / 3 - 1, dx = t % 3 - 1;
            bool inval = (hc == 0 && dy == -1) || (hc == 2 && dy == 1) ||
                         (wc == 0 && dx == -1) || (wc == 2 && dx == 1);
            if (inval) corr += 32 - 2 * __popc(WP[cv * 288 + co * 9 + t]);
          }
          CORR[cv * 288 + cls * 32 + co] = corr;
        }
        __syncthreads();
      }
    } else {
      // ---- halo zero for P and P2: 2*32*968 = 61952 words, blocks 1600..1841
      int k = (b - 1600) * 256 + tid;
      uint32_t* buf = (k < 32 * HALO_WORDS) ? P : P2;
      int j = k % (32 * HALO_WORDS);
      int img = j / HALO_WORDS;
      int r = j - img * HALO_WORDS;
      int pr, pc;
      if (r < 164)      { pr = 0;   pc = r; }
      else if (r < 328) { pr = 161; pc = r - 164; }
      else {
        int k2 = r - 328;
        pr = 1 + (k2 >> 2);
        int q = k2 & 3;
        pc = (q == 0) ? 0 : (160 + q);
      }
      buf[img * PIMG + pr * PRS + pc] = 0;
    }
    return;
  }

  // ---- pack: 4 threads per 8-pixel group; each thread loads its 8-channel octet
  //      as 16 independent float4 (all in flight), then shfl_xor OR-combine.
  int g = b * 256 + tid;
  int grp = g >> 2;              // 8-pixel group, 0..102399
  int k = g & 3;                 // channel octet
  int p0 = grp * 8;
  int n = p0 / HWL;
  int i = p0 - n * HWL;
  const float* xb = x + (size_t)n * CH * HWL + i + (size_t)(k * 8) * HWL;
  float4 a0 = *reinterpret_cast<const float4*>(xb + 0 * HWL);
  float4 b0 = *reinterpret_cast<const float4*>(xb + 0 * HWL + 4);
  float4 a1 = *reinterpret_cast<const float4*>(xb + 1 * HWL);
  float4 b1 = *reinterpret_cast<const float4*>(xb + 1 * HWL + 4);
  float4 a2 = *reinterpret_cast<const float4*>(xb + 2 * HWL);
  float4 b2 = *reinterpret_cast<const float4*>(xb + 2 * HWL + 4);
  float4 a3 = *reinterpret_cast<const float4*>(xb + 3 * HWL);
  float4 b3 = *reinterpret_cast<const float4*>(xb + 3 * HWL + 4);
  float4 a4 = *reinterpret_cast<const float4*>(xb + 4 * HWL);
  float4 b4 = *reinterpret_cast<const float4*>(xb + 4 * HWL + 4);
  float4 a5 = *reinterpret_cast<const float4*>(xb + 5 * HWL);
  float4 b5 = *reinterpret_cast<const float4*>(xb + 5 * HWL + 4);
  float4 a6 = *reinterpret_cast<const float4*>(xb + 6 * HWL);
  float4 b6 = *reinterpret_cast<const float4*>(xb + 6 * HWL + 4);
  float4 a7 = *reinterpret_cast<const float4*>(xb + 7 * HWL);
  float4 b7 = *reinterpret_cast<const float4*>(xb + 7 * HWL + 4);

  uint32_t q0 = 0, q1 = 0, q2 = 0, q3 = 0, q4 = 0, q5 = 0, q6 = 0, q7 = 0;
  int c0 = k * 8;
  #define ACC(j, aj, bj)                                        \
    { uint32_t m = 1u << (c0 + j);                              \
      if (aj.x > 0.f) q0 |= m; if (aj.y > 0.f) q1 |= m;         \
      if (aj.z > 0.f) q2 |= m; if (aj.w > 0.f) q3 |= m;         \
      if (bj.x > 0.f) q4 |= m; if (bj.y > 0.f) q5 |= m;         \
      if (bj.z > 0.f) q6 |= m; if (bj.w > 0.f) q7 |= m; }
  ACC(0, a0, b0) ACC(1, a1, b1) ACC(2, a2, b2) ACC(3, a3, b3)
  ACC(4, a4, b4) ACC(5, a5, b5) ACC(6, a6, b6) ACC(7, a7, b7)
  #undef ACC

  // OR-combine across the 4 lanes of the group (groups never cross a wave)
  q0 |= __shfl_xor(q0, 1); q1 |= __shfl_xor(q1, 1);
  q2 |= __shfl_xor(q2, 1); q3 |= __shfl_xor(q3, 1);
  q4 |= __shfl_xor(q4, 1); q5 |= __shfl_xor(q5, 1);
  q6 |= __shfl_xor(q6, 1); q7 |= __shfl_xor(q7, 1);
  q0 |= __shfl_xor(q0, 2); q1 |= __shfl_xor(q1, 2);
  q2 |= __shfl_xor(q2, 2); q3 |= __shfl_xor(q3, 2);
  q4 |= __shfl_xor(q4, 2); q5 |= __shfl_xor(q5, 2);
  q6 |= __shfl_xor(q6, 2); q7 |= __shfl_xor(q7, 2);

  int h = i / WW, w = i - (i / WW) * WW;
  uint32_t* pw = P + n * PIMG + (h + 1) * PRS + (w + 1);
  uint32_t wa = (k == 0) ? q0 : (k == 1) ? q1 : (k == 2) ? q2 : q3;
  uint32_t wb = (k == 0) ? q4 : (k == 1) ? q5 : (k == 2) ? q6 : q7;
  pw[k] = wa;
  pw[k + 4] = wb;
}

// ================ K2/K4: conv (recompute) -> per-channel stats only ================
__global__ __launch_bounds__(256) void conv_stats(const uint32_t* __restrict__ P,
    const uint32_t* __restrict__ WP, const int* __restrict__ CORR,
    StatLine* __restrict__ sb)
{
  __shared__ uint32_t wsh[288];
  __shared__ int csh[288];
  __shared__ int ls1[32], ls2[32];
  const int tid = threadIdx.x;
  for (int i = tid; i < 288; i += 256) { wsh[i] = WP[i]; csh[i] = CORR[i]; }
  if (tid < 32) { ls1[tid] = 0; ls2[tid] = 0; }
  __syncthreads();

  int g = blockIdx.x * 256 + tid;
  int w4 = g % 40;
  int t1 = g / 40;
  int h = t1 % 160;
  int n = t1 / 160;

  const uint32_t* base = P + n * PIMG + h * PRS + w4 * 4;
  uint32_t r[3][6];
  #pragma unroll
  for (int dy = 0; dy < 3; ++dy) {
    uint4 a = *reinterpret_cast<const uint4*>(base + dy * PRS);
    uint2 bw = *reinterpret_cast<const uint2*>(base + dy * PRS + 4);
    r[dy][0] = a.x; r[dy][1] = a.y; r[dy][2] = a.z; r[dy][3] = a.w;
    r[dy][4] = bw.x; r[dy][5] = bw.y;
  }

  int rowc = (h == 0) ? 0 : ((h == 159) ? 6 : 3);
  int cls0  = rowc + ((w4 == 0) ? 0 : 1);
  int cls12 = rowc + 1;
  int cls3  = rowc + ((w4 == 39) ? 2 : 1);
  int lane = tid & 63;

  #pragma unroll
  for (int co = 0; co < 32; ++co) {
    int a0, a1, a2, a3;
    conv4(r, wsh, co, a0, a1, a2, a3);
    int d0 = 288 - 2 * a0 - csh[cls0 * 32 + co];
    int d1 = 288 - 2 * a1 - csh[cls12 * 32 + co];
    int d2 = 288 - 2 * a2 - csh[cls12 * 32 + co];
    int d3 = 288 - 2 * a3 - csh[cls3 * 32 + co];
    int ds = d0 + d1 + d2 + d3;
    int sq = d0 * d0 + d1 * d1 + d2 * d2 + d3 * d3;
    #pragma unroll
    for (int off = 32; off > 0; off >>= 1) {
      ds += __shfl_down(ds, off);
      sq += __shfl_down(sq, off);
    }
    if (lane == 0) { atomicAdd(&ls1[co], ds); atomicAdd(&ls2[co], sq); }
  }
  __syncthreads();
  if (tid < 32) {
    atomicAdd(&sb[tid].s1, ls1[tid]);
    atomicAdd(&sb[tid].s2, (unsigned long long)(long long)ls2[tid]);
  }
}

// ================ K3: conv1 recompute + BN1 + residual(x) -> INNER bf16 + P2 bits ===
__global__ __launch_bounds__(256, 2) void conv_bn1(const uint32_t* __restrict__ P,
    const uint32_t* __restrict__ WP, const int* __restrict__ CORR,
    const float* __restrict__ x, const float* __restrict__ SCp,
    const StatLine* __restrict__ sb, const float* __restrict__ gamma,
    const float* __restrict__ beta, unsigned short* __restrict__ INNER,
    uint32_t* __restrict__ P2)
{
  __shared__ uint32_t wsh[288];
  __shared__ int csh[288];
  __shared__ float Ash[32], Bsh[32];
  const int tid = threadIdx.x;
  for (int i = tid; i < 288; i += 256) { wsh[i] = WP[i]; csh[i] = CORR[i]; }
  if (tid < 32) {
    double sc = (double)SCp[0];
    double m  = sc * (double)sb[tid].s1 / (double)NPIX;
    double ms = sc * sc * (double)(long long)sb[tid].s2 / (double)NPIX;
    float inv = (float)(1.0 / sqrt(ms - m * m + 1e-5));
    float gm = gamma[tid];
    Ash[tid] = gm * inv * (float)sc;
    Bsh[tid] = beta[tid] - gm * inv * (float)m;
  }
  __syncthreads();

  int g = blockIdx.x * 256 + tid;
  int w4 = g % 40;
  int t1 = g / 40;
  int h = t1 % 160;
  int n = t1 / 160;

  const uint32_t* base = P + n * PIMG + h * PRS + w4 * 4;
  uint32_t r[3][6];
  #pragma unroll
  for (int dy = 0; dy < 3; ++dy) {
    uint4 a = *reinterpret_cast<const uint4*>(base + dy * PRS);
    uint2 bw = *reinterpret_cast<const uint2*>(base + dy * PRS + 4);
    r[dy][0] = a.x; r[dy][1] = a.y; r[dy][2] = a.z; r[dy][3] = a.w;
    r[dy][4] = bw.x; r[dy][5] = bw.y;
  }
  int rowc = (h == 0) ? 0 : ((h == 159) ? 6 : 3);
  int cls0  = rowc + ((w4 == 0) ? 0 : 1);
  int cls12 = rowc + 1;
  int cls3  = rowc + ((w4 == 39) ? 2 : 1);

  int i = h * WW + w4 * 4;
  size_t pbase = (size_t)n * CH * HWL + i;

  // all 32 residual loads issued upfront (in-order consumption overlaps compute)
  float4 xv[32];
  #pragma unroll
  for (int j = 0; j < 32; ++j)
    xv[j] = *reinterpret_cast<const float4*>(x + pbase + (size_t)j * HWL);

  uint32_t bb0 = 0, bb1 = 0, bb2 = 0, bb3 = 0;
  #pragma unroll
  for (int co = 0; co < 32; ++co) {
    int a0, a1, a2, a3;
    conv4(r, wsh, co, a0, a1, a2, a3);
    int d0 = 288 - 2 * a0 - csh[cls0 * 32 + co];
    int d1 = 288 - 2 * a1 - csh[cls12 * 32 + co];
    int d2 = 288 - 2 * a2 - csh[cls12 * 32 + co];
    int d3 = 288 - 2 * a3 - csh[cls3 * 32 + co];
    float A = Ash[co], Bv = Bsh[co];
    float v0 = fmaf(A, (float)d0, Bv) + xv[co].x;
    float v1 = fmaf(A, (float)d1, Bv) + xv[co].y;
    float v2 = fmaf(A, (float)d2, Bv) + xv[co].z;
    float v3 = fmaf(A, (float)d3, Bv) + xv[co].w;
    ushort4 o; o.x = f2bf(v0); o.y = f2bf(v1); o.z = f2bf(v2); o.w = f2bf(v3);
    *reinterpret_cast<ushort4*>(INNER + pbase + (size_t)co * HWL) = o;
    uint32_t m = 1u << co;
    if (v0 > 0.f) bb0 |= m;
    if (v1 > 0.f) bb1 |= m;
    if (v2 > 0.f) bb2 |= m;
    if (v3 > 0.f) bb3 |= m;
  }
  uint32_t* pw = P2 + n * PIMG + (h + 1) * PRS + (w4 * 4 + 1);
  pw[0] = bb0; pw[1] = bb1; pw[2] = bb2; pw[3] = bb3;
}

// ================ K5: conv2 recompute + BN2 + residual(INNER) -> out fp32 ==========
__global__ __launch_bounds__(256, 2) void conv_bn2(const uint32_t* __restrict__ P2,
    const uint32_t* __restrict__ WP, const int* __restrict__ CORR,
    const unsigned short* __restrict__ INNER, const float* __restrict__ SCp,
    const StatLine* __restrict__ sb, const float* __restrict__ gamma,
    const float* __restrict__ beta, float* __restrict__ out)
{
  __shared__ uint32_t wsh[288];
  __shared__ int csh[288];
  __shared__ float Ash[32], Bsh[32];
  const int tid = threadIdx.x;
  for (int i = tid; i < 288; i += 256) { wsh[i] = WP[i]; csh[i] = CORR[i]; }
  if (tid < 32) {
    double sc = (double)SCp[0];
    double m  = sc * (double)sb[tid].s1 / (double)NPIX;
    double ms = sc * sc * (double)(long long)sb[tid].s2 / (double)NPIX;
    float inv = (float)(1.0 / sqrt(ms - m * m + 1e-5));
    float gm = gamma[tid];
    Ash[tid] = gm * inv * (float)sc;
    Bsh[tid] = beta[tid] - gm * inv * (float)m;
  }
  __syncthreads();

  int g = blockIdx.x * 256 + tid;
  int w4 = g % 40;
  int t1 = g / 40;
  int h = t1 % 160;
  int n = t1 / 160;

  const uint32_t* base = P2 + n * PIMG + h * PRS + w4 * 4;
  uint32_t r[3][6];
  #pragma unroll
  for (int dy = 0; dy < 3; ++dy) {
    uint4 a = *reinterpret_cast<const uint4*>(base + dy * PRS);
    uint2 bw = *reinterpret_cast<const uint2*>(base + dy * PRS + 4);
    r[dy][0] = a.x; r[dy][1] = a.y; r[dy][2] = a.z; r[dy][3] = a.w;
    r[dy][4] = bw.x; r[dy][5] = bw.y;
  }
  int rowc = (h == 0) ? 0 : ((h == 159) ? 6 : 3);
  int cls0  = rowc + ((w4 == 0) ? 0 : 1);
  int cls12 = rowc + 1;
  int cls3  = rowc + ((w4 == 39) ? 2 : 1);

  int i = h * WW + w4 * 4;
  size_t pbase = (size_t)n * CH * HWL + i;

  ushort4 iv[32];
  #pragma unroll
  for (int j = 0; j < 32; ++j)
    iv[j] = *reinterpret_cast<const ushort4*>(INNER + pbase + (size_t)j * HWL);

  #pragma unroll
  for (int co = 0; co < 32; ++co) {
    int a0, a1, a2, a3;
    conv4(r, wsh, co, a0, a1, a2, a3);
    int d0 = 288 - 2 * a0 - csh[cls0 * 32 + co];
    int d1 = 288 - 2 * a1 - csh[cls12 * 32 + co];
    int d2 = 288 - 2 * a2 - csh[cls12 * 32 + co];
    int d3 = 288 - 2 * a3 - csh[cls3 * 32 + co];
    float A = Ash[co], Bv = Bsh[co];
    float4 o;
    o.x = fmaf(A, (float)d0, Bv) + bf2f(iv[co].x);
    o.y = fmaf(A, (float)d1, Bv) + bf2f(iv[co].y);
    o.z = fmaf(A, (float)d2, Bv) + bf2f(iv[co].z);
    o.w = fmaf(A, (float)d3, Bv) + bf2f(iv[co].w);
    *reinterpret_cast<float4*>(out + pbase + (size_t)co * HWL) = o;
  }
}

extern "C" void kernel_launch(void* const* d_in, const int* in_sizes, int n_in,
                              void* d_out, int out_size, void* d_ws, size_t ws_size,
                              hipStream_t stream)
{
  (void)in_sizes; (void)n_in; (void)out_size; (void)ws_size;
  const float* x  = (const float*)d_in[0];
  const float* w1 = (const float*)d_in[1];
  const float* g1 = (const float*)d_in[2];
  const float* b1 = (const float*)d_in[3];
  const float* w2 = (const float*)d_in[4];
  const float* g2 = (const float*)d_in[5];
  const float* b2 = (const float*)d_in[6];
  float* out = (float*)d_out;
  char* ws = (char*)d_ws;

  uint32_t*       P     = (uint32_t*)(ws + OFF_P);
  uint32_t*       P2    = (uint32_t*)(ws + OFF_P2);
  unsigned short* INNER = (unsigned short*)(ws + OFF_INNER);
  uint32_t*       WP    = (uint32_t*)(ws + OFF_WP);
  int*            CORR  = (int*)(ws + OFF_CORR);
  float*          SC    = (float*)(ws + OFF_SC);
  StatLine*       SB    = (StatLine*)(ws + OFF_SB);

  pack_prep<<<1843, 256, 0, stream>>>(x, w1, w2, P, P2, WP, CORR, SC, SB);
  conv_stats<<<800, 256, 0, stream>>>(P, WP, CORR, SB);
  conv_bn1<<<800, 256, 0, stream>>>(P, WP, CORR, x, SC, SB, g1, b1, INNER, P2);
  conv_stats<<<800, 256, 0, stream>>>(P2, WP + 288, CORR + 288, SB + 32);
  conv_bn2<<<800, 256, 0, stream>>>(P2, WP + 288, CORR + 288, INNER, SC + 1, SB + 32, g2, b2, out);
}

// Round 7
// 174.564 us; speedup vs baseline: 1.1745x; 1.1745x over previous
//
#include <hip/hip_runtime.h>
#include <stdint.h>

#define NIMG 32
#define CH 32
#define HH 160
#define WW 160
#define HWL (HH*WW)            // 25600
#define PRS 164                // padded row stride (words)
#define PHH 162
#define PIMG (PHH*PRS)         // 26568 words per padded image
#define NPIX (NIMG*HWL)        // 819200 pixels
#define HALO_WORDS 968         // per image: 2*164 + 160*4

// workspace layout (bytes)
#define OFF_P     0
#define OFF_P2    3400704                    // P : 32*26568*4
#define OFF_INNER (OFF_P2 + 3400704)         // P2: same
#define OFF_WP    (OFF_INNER + 52428800)     // inner: bf16
#define OFF_CORR  (OFF_WP + 2304)
#define OFF_SC    (OFF_CORR + 2304)
#define OFF_SB    (OFF_SC + 128)             // 64 StatLines x 128 B

struct StatLine {                            // one 128B line per channel
  int s1; int pad0; unsigned long long s2; char pad[112];
};

#define AS1 __attribute__((address_space(1)))
#define AS3 __attribute__((address_space(3)))
__device__ __forceinline__ void dma16(const float* g, float* l) {
  // global -> LDS direct DMA, 16 B per lane; LDS dest = wave-uniform base + lane*16
  __builtin_amdgcn_global_load_lds((const AS1 void*)g, (AS3 void*)l, 16, 0, 0);
}

__device__ __forceinline__ unsigned short f2bf(float f) {   // RNE float->bf16
  unsigned u = __float_as_uint(f);
  u += 0x7fffu + ((u >> 16) & 1u);
  return (unsigned short)(u >> 16);
}
__device__ __forceinline__ float bf2f(unsigned short u) {
  return __uint_as_float((uint32_t)u << 16);
}

__device__ __forceinline__ void conv4(const uint32_t r[3][6], const uint32_t* wsh,
                                      int co, int& a0, int& a1, int& a2, int& a3)
{
  a0 = a1 = a2 = a3 = 0;
  #pragma unroll
  for (int dy = 0; dy < 3; ++dy) {
    #pragma unroll
    for (int dx = 0; dx < 3; ++dx) {
      uint32_t wvv = wsh[co * 9 + dy * 3 + dx];
      a0 += __popc(r[dy][0 + dx] ^ wvv);
      a1 += __popc(r[dy][1 + dx] ^ wvv);
      a2 += __popc(r[dy][2 + dx] ^ wvv);
      a3 += __popc(r[dy][3 + dx] ^ wvv);
    }
  }
}

// ================ K1: pack x via LDS DMA staging + prep + halo zero ================
// blocks 0..1599: pack (512 px x 32 ch tile); 1600..1841: halo zero; 1842: prep
__global__ __launch_bounds__(256) void pack_prep(const float* __restrict__ x,
    const float* __restrict__ w1, const float* __restrict__ w2,
    uint32_t* __restrict__ P, uint32_t* __restrict__ P2, uint32_t* __restrict__ WP,
    int* __restrict__ CORR, float* __restrict__ SC, StatLine* __restrict__ SB)
{
  __shared__ float lds[16384];               // 64 KB, reused by all branches
  const int tid = threadIdx.x;
  const int b = blockIdx.x;

  if (b >= 1600) {
    if (b == 1842) {
      // ---- prep: zero stats, stage w in LDS, scale, bit-pack, corrections
      int* z = (int*)SB;
      for (int i = tid; i < 2048; i += 256) z[i] = 0;
      float* wl  = lds;                      // 9216 floats
      float* red = lds + 9216;               // 256 floats
      uint32_t* wpl = (uint32_t*)(lds + 9600); // 288 words
      for (int cv = 0; cv < 2; ++cv) {
        const float* w = cv ? w2 : w1;
        float s = 0.f;
        #pragma unroll
        for (int j = 0; j < 9; ++j) {
          float4 v = *reinterpret_cast<const float4*>(w + (j * 256 + tid) * 4);
          *reinterpret_cast<float4*>(wl + (j * 256 + tid) * 4) = v;
          s += fabsf(v.x) + fabsf(v.y) + fabsf(v.z) + fabsf(v.w);
        }
        red[tid] = s;
        __syncthreads();
        for (int st = 128; st > 0; st >>= 1) {
          if (tid < st) red[tid] += red[tid + st];
          __syncthreads();
        }
        if (tid == 0) SC[cv] = red[0] / 9216.0f;
        for (int i = tid; i < 288; i += 256) {
          int co = i / 9, t = i - co * 9;
          uint32_t bw = 0;
          for (int ci = 0; ci < 32; ++ci)
            bw |= (wl[(co * 32 + ci) * 9 + t] > 0.0f) ? (1u << ci) : 0u;
          WP[cv * 288 + i] = bw;
          wpl[i] = bw;
        }
        __syncthreads();
        for (int i = tid; i < 288; i += 256) {
          int cls = i / 32, co = i - cls * 32;
          int hc = cls / 3, wc = cls - hc * 3;
          int corr = 0;
          for (int t = 0; t < 9; ++t) {
            int dy = t / 3 - 1, dx = t % 3 - 1;
            bool inval = (hc == 0 && dy == -1) || (hc == 2 && dy == 1) ||
                         (wc == 0 && dx == -1) || (wc == 2 && dx == 1);
            if (inval) corr += 32 - 2 * __popc(wpl[co * 9 + t]);
          }
          CORR[cv * 288 + cls * 32 + co] = corr;
        }
        __syncthreads();
      }
    } else {
      // ---- halo zero for P and P2: 2*32*968 = 61952 words, blocks 1600..1841
      int k = (b - 1600) * 256 + tid;
      uint32_t* buf = (k < 32 * HALO_WORDS) ? P : P2;
      int j = k % (32 * HALO_WORDS);
      int img = j / HALO_WORDS;
      int r = j - img * HALO_WORDS;
      int pr, pc;
      if (r < 164)      { pr = 0;   pc = r; }
      else if (r < 328) { pr = 161; pc = r - 164; }
      else {
        int k2 = r - 328;
        pr = 1 + (k2 >> 2);
        int q = k2 & 3;
        pc = (q == 0) ? 0 : (160 + q);
      }
      buf[img * PIMG + pr * PRS + pc] = 0;
    }
    return;
  }

  // ---- pack: tile = 512 px x 32 ch staged to LDS [c][512] via 16 DMA/thread
  int n = b / 50;
  int p0 = (b - n * 50) * 512;
  const float* xb = x + (size_t)n * CH * HWL + p0;
  #pragma unroll
  for (int it = 0; it < 16; ++it) {
    int c = it * 2 + (tid >> 7);             // uniform per wave
    const float* g = xb + (size_t)c * HWL + (tid & 127) * 4;
    float* l = lds + it * 1024 + (tid >> 6) * 256;  // wave-uniform base
    dma16(g, l);
  }
  __syncthreads();                            // drains vmcnt -> LDS tile ready

  const float2* l2 = (const float2*)lds;
  uint32_t b0 = 0, b1 = 0;
  #pragma unroll
  for (int c = 0; c < 32; ++c) {
    float2 v = l2[c * 256 + tid];
    if (v.x > 0.f) b0 |= 1u << c;
    if (v.y > 0.f) b1 |= 1u << c;
  }
  int pxg = p0 + tid * 2;                     // even -> pair stays in one row
  int h = pxg / WW, w = pxg - h * WW;
  uint32_t* pw = P + n * PIMG + (h + 1) * PRS + (w + 1);
  pw[0] = b0; pw[1] = b1;
}

// ================ K2/K4: conv (recompute) -> per-channel stats only ================
__global__ __launch_bounds__(256) void conv_stats(const uint32_t* __restrict__ P,
    const uint32_t* __restrict__ WP, const int* __restrict__ CORR,
    StatLine* __restrict__ sb)
{
  __shared__ uint32_t wsh[288];
  __shared__ int csh[288];
  __shared__ int ls1[32], ls2[32];
  const int tid = threadIdx.x;
  for (int i = tid; i < 288; i += 256) { wsh[i] = WP[i]; csh[i] = CORR[i]; }
  if (tid < 32) { ls1[tid] = 0; ls2[tid] = 0; }
  __syncthreads();

  int g = blockIdx.x * 256 + tid;
  int w4 = g % 40;
  int t1 = g / 40;
  int h = t1 % 160;
  int n = t1 / 160;

  const uint32_t* base = P + n * PIMG + h * PRS + w4 * 4;
  uint32_t r[3][6];
  #pragma unroll
  for (int dy = 0; dy < 3; ++dy) {
    uint4 a = *reinterpret_cast<const uint4*>(base + dy * PRS);
    uint2 bw = *reinterpret_cast<const uint2*>(base + dy * PRS + 4);
    r[dy][0] = a.x; r[dy][1] = a.y; r[dy][2] = a.z; r[dy][3] = a.w;
    r[dy][4] = bw.x; r[dy][5] = bw.y;
  }

  int rowc = (h == 0) ? 0 : ((h == 159) ? 6 : 3);
  int cls0  = rowc + ((w4 == 0) ? 0 : 1);
  int cls12 = rowc + 1;
  int cls3  = rowc + ((w4 == 39) ? 2 : 1);
  int lane = tid & 63;

  #pragma unroll
  for (int co = 0; co < 32; ++co) {
    int a0, a1, a2, a3;
    conv4(r, wsh, co, a0, a1, a2, a3);
    int d0 = 288 - 2 * a0 - csh[cls0 * 32 + co];
    int d1 = 288 - 2 * a1 - csh[cls12 * 32 + co];
    int d2 = 288 - 2 * a2 - csh[cls12 * 32 + co];
    int d3 = 288 - 2 * a3 - csh[cls3 * 32 + co];
    int ds = d0 + d1 + d2 + d3;
    int sq = d0 * d0 + d1 * d1 + d2 * d2 + d3 * d3;
    #pragma unroll
    for (int off = 32; off > 0; off >>= 1) {
      ds += __shfl_down(ds, off);
      sq += __shfl_down(sq, off);
    }
    if (lane == 0) { atomicAdd(&ls1[co], ds); atomicAdd(&ls2[co], sq); }
  }
  __syncthreads();
  if (tid < 32) {
    atomicAdd(&sb[tid].s1, ls1[tid]);
    atomicAdd(&sb[tid].s2, (unsigned long long)(long long)ls2[tid]);
  }
}

// ================ K3: conv1 recompute + BN1 + residual(x) -> INNER bf16 + P2 bits ===
__global__ __launch_bounds__(256, 2) void conv_bn1(const uint32_t* __restrict__ P,
    const uint32_t* __restrict__ WP, const int* __restrict__ CORR,
    const float* __restrict__ x, const float* __restrict__ SCp,
    const StatLine* __restrict__ sb, const float* __restrict__ gamma,
    const float* __restrict__ beta, unsigned short* __restrict__ INNER,
    uint32_t* __restrict__ P2)
{
  __shared__ uint32_t wsh[288];
  __shared__ int csh[288];
  __shared__ float Ash[32], Bsh[32];
  const int tid = threadIdx.x;
  for (int i = tid; i < 288; i += 256) { wsh[i] = WP[i]; csh[i] = CORR[i]; }
  if (tid < 32) {
    double sc = (double)SCp[0];
    double m  = sc * (double)sb[tid].s1 / (double)NPIX;
    double ms = sc * sc * (double)(long long)sb[tid].s2 / (double)NPIX;
    float inv = (float)(1.0 / sqrt(ms - m * m + 1e-5));
    float gm = gamma[tid];
    Ash[tid] = gm * inv * (float)sc;
    Bsh[tid] = beta[tid] - gm * inv * (float)m;
  }
  __syncthreads();

  int g = blockIdx.x * 256 + tid;
  int w4 = g % 40;
  int t1 = g / 40;
  int h = t1 % 160;
  int n = t1 / 160;

  const uint32_t* base = P + n * PIMG + h * PRS + w4 * 4;
  uint32_t r[3][6];
  #pragma unroll
  for (int dy = 0; dy < 3; ++dy) {
    uint4 a = *reinterpret_cast<const uint4*>(base + dy * PRS);
    uint2 bw = *reinterpret_cast<const uint2*>(base + dy * PRS + 4);
    r[dy][0] = a.x; r[dy][1] = a.y; r[dy][2] = a.z; r[dy][3] = a.w;
    r[dy][4] = bw.x; r[dy][5] = bw.y;
  }
  int rowc = (h == 0) ? 0 : ((h == 159) ? 6 : 3);
  int cls0  = rowc + ((w4 == 0) ? 0 : 1);
  int cls12 = rowc + 1;
  int cls3  = rowc + ((w4 == 39) ? 2 : 1);

  int i = h * WW + w4 * 4;
  size_t pbase = (size_t)n * CH * HWL + i;

  float4 xv[32];
  #pragma unroll
  for (int j = 0; j < 32; ++j)
    xv[j] = *reinterpret_cast<const float4*>(x + pbase + (size_t)j * HWL);

  uint32_t bb0 = 0, bb1 = 0, bb2 = 0, bb3 = 0;
  #pragma unroll
  for (int co = 0; co < 32; ++co) {
    int a0, a1, a2, a3;
    conv4(r, wsh, co, a0, a1, a2, a3);
    int d0 = 288 - 2 * a0 - csh[cls0 * 32 + co];
    int d1 = 288 - 2 * a1 - csh[cls12 * 32 + co];
    int d2 = 288 - 2 * a2 - csh[cls12 * 32 + co];
    int d3 = 288 - 2 * a3 - csh[cls3 * 32 + co];
    float A = Ash[co], Bv = Bsh[co];
    float v0 = fmaf(A, (float)d0, Bv) + xv[co].x;
    float v1 = fmaf(A, (float)d1, Bv) + xv[co].y;
    float v2 = fmaf(A, (float)d2, Bv) + xv[co].z;
    float v3 = fmaf(A, (float)d3, Bv) + xv[co].w;
    ushort4 o; o.x = f2bf(v0); o.y = f2bf(v1); o.z = f2bf(v2); o.w = f2bf(v3);
    *reinterpret_cast<ushort4*>(INNER + pbase + (size_t)co * HWL) = o;
    uint32_t m = 1u << co;
    if (v0 > 0.f) bb0 |= m;
    if (v1 > 0.f) bb1 |= m;
    if (v2 > 0.f) bb2 |= m;
    if (v3 > 0.f) bb3 |= m;
  }
  uint32_t* pw = P2 + n * PIMG + (h + 1) * PRS + (w4 * 4 + 1);
  pw[0] = bb0; pw[1] = bb1; pw[2] = bb2; pw[3] = bb3;
}

// ================ K5: conv2 recompute + BN2 + residual(INNER) -> out fp32 ==========
__global__ __launch_bounds__(256, 2) void conv_bn2(const uint32_t* __restrict__ P2,
    const uint32_t* __restrict__ WP, const int* __restrict__ CORR,
    const unsigned short* __restrict__ INNER, const float* __restrict__ SCp,
    const StatLine* __restrict__ sb, const float* __restrict__ gamma,
    const float* __restrict__ beta, float* __restrict__ out)
{
  __shared__ uint32_t wsh[288];
  __shared__ int csh[288];
  __shared__ float Ash[32], Bsh[32];
  const int tid = threadIdx.x;
  for (int i = tid; i < 288; i += 256) { wsh[i] = WP[i]; csh[i] = CORR[i]; }
  if (tid < 32) {
    double sc = (double)SCp[0];
    double m  = sc * (double)sb[tid].s1 / (double)NPIX;
    double ms = sc * sc * (double)(long long)sb[tid].s2 / (double)NPIX;
    float inv = (float)(1.0 / sqrt(ms - m * m + 1e-5));
    float gm = gamma[tid];
    Ash[tid] = gm * inv * (float)sc;
    Bsh[tid] = beta[tid] - gm * inv * (float)m;
  }
  __syncthreads();

  int g = blockIdx.x * 256 + tid;
  int w4 = g % 40;
  int t1 = g / 40;
  int h = t1 % 160;
  int n = t1 / 160;

  const uint32_t* base = P2 + n * PIMG + h * PRS + w4 * 4;
  uint32_t r[3][6];
  #pragma unroll
  for (int dy = 0; dy < 3; ++dy) {
    uint4 a = *reinterpret_cast<const uint4*>(base + dy * PRS);
    uint2 bw = *reinterpret_cast<const uint2*>(base + dy * PRS + 4);
    r[dy][0] = a.x; r[dy][1] = a.y; r[dy][2] = a.z; r[dy][3] = a.w;
    r[dy][4] = bw.x; r[dy][5] = bw.y;
  }
  int rowc = (h == 0) ? 0 : ((h == 159) ? 6 : 3);
  int cls0  = rowc + ((w4 == 0) ? 0 : 1);
  int cls12 = rowc + 1;
  int cls3  = rowc + ((w4 == 39) ? 2 : 1);

  int i = h * WW + w4 * 4;
  size_t pbase = (size_t)n * CH * HWL + i;

  ushort4 iv[32];
  #pragma unroll
  for (int j = 0; j < 32; ++j)
    iv[j] = *reinterpret_cast<const ushort4*>(INNER + pbase + (size_t)j * HWL);

  #pragma unroll
  for (int co = 0; co < 32; ++co) {
    int a0, a1, a2, a3;
    conv4(r, wsh, co, a0, a1, a2, a3);
    int d0 = 288 - 2 * a0 - csh[cls0 * 32 + co];
    int d1 = 288 - 2 * a1 - csh[cls12 * 32 + co];
    int d2 = 288 - 2 * a2 - csh[cls12 * 32 + co];
    int d3 = 288 - 2 * a3 - csh[cls3 * 32 + co];
    float A = Ash[co], Bv = Bsh[co];
    float4 o;
    o.x = fmaf(A, (float)d0, Bv) + bf2f(iv[co].x);
    o.y = fmaf(A, (float)d1, Bv) + bf2f(iv[co].y);
    o.z = fmaf(A, (float)d2, Bv) + bf2f(iv[co].z);
    o.w = fmaf(A, (float)d3, Bv) + bf2f(iv[co].w);
    *reinterpret_cast<float4*>(out + pbase + (size_t)co * HWL) = o;
  }
}

extern "C" void kernel_launch(void* const* d_in, const int* in_sizes, int n_in,
                              void* d_out, int out_size, void* d_ws, size_t ws_size,
                              hipStream_t stream)
{
  (void)in_sizes; (void)n_in; (void)out_size; (void)ws_size;
  const float* x  = (const float*)d_in[0];
  const float* w1 = (const float*)d_in[1];
  const float* g1 = (const float*)d_in[2];
  const float* b1 = (const float*)d_in[3];
  const float* w2 = (const float*)d_in[4];
  const float* g2 = (const float*)d_in[5];
  const float* b2 = (const float*)d_in[6];
  float* out = (float*)d_out;
  char* ws = (char*)d_ws;

  uint32_t*       P     = (uint32_t*)(ws + OFF_P);
  uint32_t*       P2    = (uint32_t*)(ws + OFF_P2);
  unsigned short* INNER = (unsigned short*)(ws + OFF_INNER);
  uint32_t*       WP    = (uint32_t*)(ws + OFF_WP);
  int*            CORR  = (int*)(ws + OFF_CORR);
  float*          SC    = (float*)(ws + OFF_SC);
  StatLine*       SB    = (StatLine*)(ws + OFF_SB);

  pack_prep<<<1843, 256, 0, stream>>>(x, w1, w2, P, P2, WP, CORR, SC, SB);
  conv_stats<<<800, 256, 0, stream>>>(P, WP, CORR, SB);
  conv_bn1<<<800, 256, 0, stream>>>(P, WP, CORR, x, SC, SB, g1, b1, INNER, P2);
  conv_stats<<<800, 256, 0, stream>>>(P2, WP + 288, CORR + 288, SB + 32);
  conv_bn2<<<800, 256, 0, stream>>>(P2, WP + 288, CORR + 288, INNER, SC + 1, SB + 32, g2, b2, out);
}